// Round 6
// baseline (68.889 us; speedup 1.0000x reference)
//
#include <hip/hip_runtime.h>

// DividedModel: 64 towers of Dense(32,64)+ReLU -> 64x64+ReLU -> 64x64+ReLU -> 64x1.
// R5: R4's register-lean pi-trick scheme, reshaped to 16-wave (1024-thread)
// workgroups to test the blocks-per-CU residency cap: 512 blocks x 16 waves,
// each block = 1 tower x 2048 rows. Weight staging runs 4x fewer times.
// Persistent regs: W1 frags + w3 + biases. W0/W2 frags re-read from LDS per
// tile (laundered indices defeat LICM). Main loop: no barriers, no DS writes.

typedef float  f32x4 __attribute__((ext_vector_type(4)));
typedef short  bf8   __attribute__((ext_vector_type(8)));
typedef unsigned int uint4v __attribute__((ext_vector_type(4)));

static constexpr int Bsz  = 16384;
static constexpr int Idim = 32;
static constexpr int Odim = 64;
static constexpr int BPT  = 8;                     // blocks per tower
static constexpr int ROWS_PER_BLK = Bsz / BPT;     // 2048 rows
static constexpr int ROWTILES = ROWS_PER_BLK / 256; // 8 tile-steps (16 waves x 16 rows)

__device__ __forceinline__ unsigned short f2bf(float f) {   // staging only (one-time)
    unsigned int u = __builtin_bit_cast(unsigned int, f);
    unsigned int r = u + 0x7FFFu + ((u >> 16) & 1u);
    return (unsigned short)(r >> 16);
}

__device__ __forceinline__ unsigned cvt_pk(float lo, float hi) {
    unsigned d;
    asm("v_cvt_pk_bf16_f32 %0, %1, %2" : "=v"(d) : "v"(lo), "v"(hi));
    return d;
}

// pi permutation: k-slot S for input-hidden index `in` (0..63).
// in_h(S) = 32*(S>>5) + 16*((S&7)>>2) + 4*((S>>3)&3) + (S&3).
__device__ __forceinline__ int pi_slot(int in) {
    return 32 * (in >> 5) + 8 * ((in >> 2) & 3) + 4 * ((in >> 4) & 1) + (in & 3);
}

__global__ __launch_bounds__(1024) void towers_kernel(
    const float* __restrict__ x,
    const float* __restrict__ W0, const float* __restrict__ b0,
    const float* __restrict__ W1, const float* __restrict__ b1,
    const float* __restrict__ W2, const float* __restrict__ b2,
    const float* __restrict__ W3, const float* __restrict__ b3,
    float* __restrict__ out)
{
    __shared__ __align__(16) unsigned short Wt0[64 * 32];  // 4KB,  Wt0[h][i^swz]
    __shared__ __align__(16) unsigned short Wt1[64 * 64];  // 8KB,  Wt1[h][S^swz]
    __shared__ __align__(16) unsigned short Wt2[64 * 64];  // 8KB
    __shared__ __align__(16) unsigned short w3s[64];       // w3s[S] = W3[o][in(S)]
    __shared__ __align__(16) float bs[3 * 64];             // b0 | b1 | b2

    const int tid  = threadIdx.x;
    const int o    = blockIdx.x / BPT;
    const int slot = blockIdx.x % BPT;

    // ---- one-time staging: float4 loads, transposed bf16, XOR-swizzled cols ----
    for (int f = tid; f < 512; f += 1024) {                // W0: 2048 floats
        f32x4 v = *(const f32x4*)&W0[o * 2048 + f * 4];
        int i  = (f * 4) >> 6;
        int h0 = (f * 4) & 63;
#pragma unroll
        for (int j = 0; j < 4; ++j) {
            int h = h0 + j;
            Wt0[h * 32 + (i ^ ((((h >> 2) ^ h) & 3) << 3))] = f2bf(v[j]);
        }
    }
    for (int f = tid; f < 1024; f += 1024) {               // W1/W2: 4096 floats each
        f32x4 v1 = *(const f32x4*)&W1[o * 4096 + f * 4];
        f32x4 v2 = *(const f32x4*)&W2[o * 4096 + f * 4];
        int in = (f * 4) >> 6;
        int h0 = (f * 4) & 63;
        int S  = pi_slot(in);
#pragma unroll
        for (int j = 0; j < 4; ++j) {
            int h = h0 + j;
            int cw = S ^ ((((h >> 2) ^ h) & 7) << 3);
            Wt1[h * 64 + cw] = f2bf(v1[j]);
            Wt2[h * 64 + cw] = f2bf(v2[j]);
        }
    }
    if (tid < 64) {
        w3s[pi_slot(tid)] = f2bf(W3[o * 64 + tid]);
        bs[tid]       = b0[o * 64 + tid];
        bs[64 + tid]  = b1[o * 64 + tid];
        bs[128 + tid] = b2[o * 64 + tid];
    }
    __syncthreads();

    const int l = tid & 63, w = tid >> 6;   // w: 0..15 waves
    const int c = l & 15,  g = l >> 4;      // c: batch col; g: k-group / D row-group

    // ---- persistent regs: W1 frags (32), w3 (8), biases (48), c3 (4) ----
    bf8 wf1f[4][2];
#pragma unroll
    for (int n = 0; n < 4; ++n) {
        int h = n * 16 + c;
        int key = ((h >> 2) ^ h) & 7;
#pragma unroll
        for (int s = 0; s < 2; ++s)
            wf1f[n][s] = *(const bf8*)&Wt1[h * 64 + ((s * 32 + g * 8) ^ (key << 3))];
    }
    bf8 w3a[2];
    w3a[0] = *(const bf8*)&w3s[g * 8];        // broadcast rows (uniform per g)
    w3a[1] = *(const bf8*)&w3s[32 + g * 8];

    f32x4 b0f[4], b1f[4], b2f[4];
#pragma unroll
    for (int n = 0; n < 4; ++n) {
        b0f[n] = *(const f32x4*)&bs[      n * 16 + g * 4];
        b1f[n] = *(const f32x4*)&bs[ 64 + n * 16 + g * 4];
        b2f[n] = *(const f32x4*)&bs[128 + n * 16 + g * 4];
    }
    f32x4 c3 = {0.f, 0.f, 0.f, 0.f};
    if (g == 0) c3[0] = b3[o];                // b3 lands on D row 0 only

    const float* xbase = x + (slot * ROWS_PER_BLK + w * 16 + c) * Idim + g * 8;
    float* obase = out + (slot * ROWS_PER_BLK + w * 16 + c) * Odim + o;

    f32x4 nxa = *(const f32x4*)(xbase);
    f32x4 nxb = *(const f32x4*)(xbase + 4);

    for (int t = 0; t < ROWTILES; ++t) {
        f32x4 xa = nxa, xb = nxb;
        if (t + 1 < ROWTILES) {               // prefetch next tile's x (256 rows ahead)
            const float* np = xbase + (t + 1) * 256 * Idim;
            nxa = *(const f32x4*)(np);
            nxb = *(const f32x4*)(np + 4);
        }

        // ---- L0 B-frag from x ----
        uint4v xd;
        xd.x = cvt_pk(xa[0], xa[1]); xd.y = cvt_pk(xa[2], xa[3]);
        xd.z = cvt_pk(xb[0], xb[1]); xd.w = cvt_pk(xb[2], xb[3]);
        bf8 a0 = __builtin_bit_cast(bf8, xd);

        // ---- W0 frags from LDS (laundered: defeat LICM, stay transient) ----
        bf8 wf0[4];
#pragma unroll
        for (int n = 0; n < 4; ++n) {
            int h = n * 16 + c;
            int idx = h * 32 + ((g * 8) ^ ((((h >> 2) ^ h) & 3) << 3));
            asm volatile("" : "+v"(idx));
            wf0[n] = *(const bf8*)&Wt0[idx];
        }

        f32x4 acc[4];
#pragma unroll
        for (int n = 0; n < 4; ++n)   // D[hidden=16n+4g+r][batch=c], bias in C
            acc[n] = __builtin_amdgcn_mfma_f32_16x16x32_bf16(wf0[n], a0, b0f[n], 0, 0, 0);

        // ---- relu + pack (lane-local thanks to pi staging) ----
        unsigned pk[4][2];
#pragma unroll
        for (int n = 0; n < 4; ++n) {
            pk[n][0] = cvt_pk(fmaxf(acc[n][0], 0.f), fmaxf(acc[n][1], 0.f));
            pk[n][1] = cvt_pk(fmaxf(acc[n][2], 0.f), fmaxf(acc[n][3], 0.f));
        }
        bf8 Blo = __builtin_bit_cast(bf8, uint4v{pk[0][0], pk[0][1], pk[1][0], pk[1][1]});
        bf8 Bhi = __builtin_bit_cast(bf8, uint4v{pk[2][0], pk[2][1], pk[3][0], pk[3][1]});

        // ---- L1 (weights in regs) ----
#pragma unroll
        for (int n = 0; n < 4; ++n)
            acc[n] = __builtin_amdgcn_mfma_f32_16x16x32_bf16(wf1f[n][0], Blo, b1f[n], 0, 0, 0);
#pragma unroll
        for (int n = 0; n < 4; ++n)
            acc[n] = __builtin_amdgcn_mfma_f32_16x16x32_bf16(wf1f[n][1], Bhi, acc[n], 0, 0, 0);
#pragma unroll
        for (int n = 0; n < 4; ++n) {
            pk[n][0] = cvt_pk(fmaxf(acc[n][0], 0.f), fmaxf(acc[n][1], 0.f));
            pk[n][1] = cvt_pk(fmaxf(acc[n][2], 0.f), fmaxf(acc[n][3], 0.f));
        }
        Blo = __builtin_bit_cast(bf8, uint4v{pk[0][0], pk[0][1], pk[1][0], pk[1][1]});
        Bhi = __builtin_bit_cast(bf8, uint4v{pk[2][0], pk[2][1], pk[3][0], pk[3][1]});

        // ---- L2 (weights from LDS, two transient groups of 4 frags) ----
        {
            bf8 w2[4];
#pragma unroll
            for (int n = 0; n < 4; ++n) {
                int h = n * 16 + c;
                int idx = h * 64 + ((g * 8) ^ ((((h >> 2) ^ h) & 7) << 3));
                asm volatile("" : "+v"(idx));
                w2[n] = *(const bf8*)&Wt2[idx];
            }
#pragma unroll
            for (int n = 0; n < 4; ++n)
                acc[n] = __builtin_amdgcn_mfma_f32_16x16x32_bf16(w2[n], Blo, b2f[n], 0, 0, 0);
#pragma unroll
            for (int n = 0; n < 4; ++n) {
                int h = n * 16 + c;
                int idx = h * 64 + (((32 + g * 8)) ^ ((((h >> 2) ^ h) & 7) << 3));
                asm volatile("" : "+v"(idx));
                w2[n] = *(const bf8*)&Wt2[idx];
            }
#pragma unroll
            for (int n = 0; n < 4; ++n)
                acc[n] = __builtin_amdgcn_mfma_f32_16x16x32_bf16(w2[n], Bhi, acc[n], 0, 0, 0);
        }
#pragma unroll
        for (int n = 0; n < 4; ++n) {
            pk[n][0] = cvt_pk(fmaxf(acc[n][0], 0.f), fmaxf(acc[n][1], 0.f));
            pk[n][1] = cvt_pk(fmaxf(acc[n][2], 0.f), fmaxf(acc[n][3], 0.f));
        }
        Blo = __builtin_bit_cast(bf8, uint4v{pk[0][0], pk[0][1], pk[1][0], pk[1][1]});
        Bhi = __builtin_bit_cast(bf8, uint4v{pk[2][0], pk[2][1], pk[3][0], pk[3][1]});

        // ---- L3: 2 MFMAs vs broadcast w3 rows; row 0 = dot(relu(h2), w3)+b3 ----
        f32x4 acc3;
        acc3 = __builtin_amdgcn_mfma_f32_16x16x32_bf16(w3a[0], Blo, c3,   0, 0, 0);
        acc3 = __builtin_amdgcn_mfma_f32_16x16x32_bf16(w3a[1], Bhi, acc3, 0, 0, 0);

        if (g == 0)
            obase[t * 256 * Odim] = acc3[0];
    }
}

extern "C" void kernel_launch(void* const* d_in, const int* in_sizes, int n_in,
                              void* d_out, int out_size, void* d_ws, size_t ws_size,
                              hipStream_t stream) {
    const float* x  = (const float*)d_in[0];
    const float* W0 = (const float*)d_in[1];
    const float* b0 = (const float*)d_in[2];
    const float* W1 = (const float*)d_in[3];
    const float* b1 = (const float*)d_in[4];
    const float* W2 = (const float*)d_in[5];
    const float* b2 = (const float*)d_in[6];
    const float* W3 = (const float*)d_in[7];
    const float* b3 = (const float*)d_in[8];
    float* out = (float*)d_out;

    dim3 grid(Odim * BPT);   // 64 towers x 8 blocks = 512 blocks of 1024 threads
    dim3 block(1024);
    towers_kernel<<<grid, block, 0, stream>>>(x, W0, b0, W1, b1, W2, b2, W3, b3, out);
}

// Round 7
// 44.203 us; speedup vs baseline: 1.5585x; 1.5585x over previous
//
#include <hip/hip_runtime.h>

// DividedModel: 64 towers of Dense(32,64)+ReLU -> 64x64+ReLU -> 64x64+ReLU -> 64x1.
// R6: R4 grid (256thr, BPT=32) + glue removal. (1) LDS frag byte-offsets
// precomputed once, in-loop launder = 1 v_mov copy (LICM-defeat without addr
// recompute). (2) accs forced to VGPR via "+v" launder (kills accvgpr moves).
// (3) W0+W1+w3+bias hoisted; W2 read from LDS (4 shared reads/tile-pair-half).
// (4) 2-tile ILP: two independent chains per iteration, shared weight frags.

typedef float  f32x4 __attribute__((ext_vector_type(4)));
typedef short  bf8   __attribute__((ext_vector_type(8)));
typedef unsigned int uint4v __attribute__((ext_vector_type(4)));

static constexpr int Bsz  = 16384;
static constexpr int Idim = 32;
static constexpr int Odim = 64;
static constexpr int BPT  = 32;                    // blocks per tower
static constexpr int ROWTILES = (Bsz / 64) / BPT;  // 8 tiles of 64 rows per block

__device__ __forceinline__ unsigned short f2bf(float f) {   // staging only (one-time)
    unsigned int u = __builtin_bit_cast(unsigned int, f);
    unsigned int r = u + 0x7FFFu + ((u >> 16) & 1u);
    return (unsigned short)(r >> 16);
}

__device__ __forceinline__ unsigned cvt_pk(float lo, float hi) {
    unsigned d;
    asm("v_cvt_pk_bf16_f32 %0, %1, %2" : "=v"(d) : "v"(lo), "v"(hi));
    return d;
}

// pi permutation: k-slot S for input-hidden index `in` (0..63).
// in_h(S) = 32*(S>>5) + 16*((S&7)>>2) + 4*((S>>3)&3) + (S&3).
__device__ __forceinline__ int pi_slot(int in) {
    return 32 * (in >> 5) + 8 * ((in >> 2) & 3) + 4 * ((in >> 4) & 1) + (in & 3);
}

__global__ __launch_bounds__(256, 2) void towers_kernel(
    const float* __restrict__ x,
    const float* __restrict__ W0, const float* __restrict__ b0,
    const float* __restrict__ W1, const float* __restrict__ b1,
    const float* __restrict__ W2, const float* __restrict__ b2,
    const float* __restrict__ W3, const float* __restrict__ b3,
    float* __restrict__ out)
{
    __shared__ __align__(16) unsigned short Wt0[64 * 32];  // 4KB,  Wt0[h][i^swz]
    __shared__ __align__(16) unsigned short Wt1[64 * 64];  // 8KB,  Wt1[h][S^swz]
    __shared__ __align__(16) unsigned short Wt2[64 * 64];  // 8KB
    __shared__ __align__(16) unsigned short w3s[64];       // w3s[S] = W3[o][in(S)]
    __shared__ __align__(16) float bs[3 * 64];             // b0 | b1 | b2

    const int tid  = threadIdx.x;
    const int o    = blockIdx.x / BPT;
    const int slot = blockIdx.x % BPT;

    // ---- one-time staging: float4 loads, transposed bf16, XOR-swizzled cols ----
    for (int f = tid; f < 512; f += 256) {                 // W0: 2048 floats
        f32x4 v = *(const f32x4*)&W0[o * 2048 + f * 4];
        int i  = (f * 4) >> 6;
        int h0 = (f * 4) & 63;
#pragma unroll
        for (int j = 0; j < 4; ++j) {
            int h = h0 + j;
            Wt0[h * 32 + (i ^ ((((h >> 2) ^ h) & 3) << 3))] = f2bf(v[j]);
        }
    }
    for (int f = tid; f < 1024; f += 256) {                // W1/W2: 4096 floats each
        f32x4 v1 = *(const f32x4*)&W1[o * 4096 + f * 4];
        f32x4 v2 = *(const f32x4*)&W2[o * 4096 + f * 4];
        int in = (f * 4) >> 6;
        int h0 = (f * 4) & 63;
        int S  = pi_slot(in);
#pragma unroll
        for (int j = 0; j < 4; ++j) {
            int h = h0 + j;
            int cw = S ^ ((((h >> 2) ^ h) & 7) << 3);
            Wt1[h * 64 + cw] = f2bf(v1[j]);
            Wt2[h * 64 + cw] = f2bf(v2[j]);
        }
    }
    if (tid < 64) {
        w3s[pi_slot(tid)] = f2bf(W3[o * 64 + tid]);
        bs[tid]       = b0[o * 64 + tid];
        bs[64 + tid]  = b1[o * 64 + tid];
        bs[128 + tid] = b2[o * 64 + tid];
    }
    __syncthreads();

    const int l = tid & 63, w = tid >> 6;
    const int c = l & 15,  g = l >> 4;   // c: batch col; g: k-group / D row-group

    // ---- persistent weight frags: W0 (16), W1 (32), w3 (8) ----
    bf8 wf0[4], wf1f[4][2];
#pragma unroll
    for (int n = 0; n < 4; ++n) {
        int h = n * 16 + c;
        wf0[n] = *(const bf8*)&Wt0[h * 32 + ((g * 8) ^ ((((h >> 2) ^ h) & 3) << 3))];
        int key = ((h >> 2) ^ h) & 7;
#pragma unroll
        for (int s = 0; s < 2; ++s)
            wf1f[n][s] = *(const bf8*)&Wt1[h * 64 + ((s * 32 + g * 8) ^ (key << 3))];
    }
    bf8 w3a[2];
    w3a[0] = *(const bf8*)&w3s[g * 8];
    w3a[1] = *(const bf8*)&w3s[32 + g * 8];

    // ---- W2 frag BYTE offsets, precomputed once (laundered per use, 1 v_mov) ----
    int off2[4][2];
#pragma unroll
    for (int n = 0; n < 4; ++n) {
        int h = n * 16 + c;
        int key = ((h >> 2) ^ h) & 7;
#pragma unroll
        for (int s = 0; s < 2; ++s)
            off2[n][s] = 2 * (h * 64 + ((s * 32 + g * 8) ^ (key << 3)));
    }

    // ---- bias C-frags: element r of chunk n is hidden 16n+4g+r ----
    f32x4 b0f[4], b1f[4], b2f[4];
#pragma unroll
    for (int n = 0; n < 4; ++n) {
        b0f[n] = *(const f32x4*)&bs[      n * 16 + g * 4];
        b1f[n] = *(const f32x4*)&bs[ 64 + n * 16 + g * 4];
        b2f[n] = *(const f32x4*)&bs[128 + n * 16 + g * 4];
    }
    f32x4 c3 = {0.f, 0.f, 0.f, 0.f};
    if (g == 0) c3[0] = b3[o];                // b3 lands on D row 0 only

    const float* xbase = x + (slot * ROWTILES * 64 + w * 16 + c) * Idim + g * 8;
    float* obase = out + (slot * ROWTILES * 64 + w * 16 + c) * Odim + o;

    f32x4 nxa0 = *(const f32x4*)(xbase);
    f32x4 nxb0 = *(const f32x4*)(xbase + 4);
    f32x4 nxa1 = *(const f32x4*)(xbase + 2048);
    f32x4 nxb1 = *(const f32x4*)(xbase + 2052);

    for (int tt = 0; tt < ROWTILES; tt += 2) {
        f32x4 xa0 = nxa0, xb0 = nxb0, xa1 = nxa1, xb1 = nxb1;
        if (tt + 2 < ROWTILES) {              // prefetch next pair
            const float* np = xbase + (tt + 2) * 2048;
            nxa0 = *(const f32x4*)(np);
            nxb0 = *(const f32x4*)(np + 4);
            nxa1 = *(const f32x4*)(np + 2048);
            nxb1 = *(const f32x4*)(np + 2052);
        }

        // ---- L0 B-frags from x ----
        uint4v xd0, xd1;
        xd0.x = cvt_pk(xa0[0], xa0[1]); xd0.y = cvt_pk(xa0[2], xa0[3]);
        xd0.z = cvt_pk(xb0[0], xb0[1]); xd0.w = cvt_pk(xb0[2], xb0[3]);
        xd1.x = cvt_pk(xa1[0], xa1[1]); xd1.y = cvt_pk(xa1[2], xa1[3]);
        xd1.z = cvt_pk(xb1[0], xb1[1]); xd1.w = cvt_pk(xb1[2], xb1[3]);
        bf8 a0_0 = __builtin_bit_cast(bf8, xd0);
        bf8 a0_1 = __builtin_bit_cast(bf8, xd1);

        f32x4 acc0[4], acc1[4];
#pragma unroll
        for (int n = 0; n < 4; ++n) {
            acc0[n] = __builtin_amdgcn_mfma_f32_16x16x32_bf16(wf0[n], a0_0, b0f[n], 0, 0, 0);
            acc1[n] = __builtin_amdgcn_mfma_f32_16x16x32_bf16(wf0[n], a0_1, b0f[n], 0, 0, 0);
            asm("" : "+v"(acc0[n]));           // pin to VGPR (no accvgpr round-trip)
            asm("" : "+v"(acc1[n]));
        }

        // ---- relu + pack ----
        unsigned p0[4][2], p1[4][2];
#pragma unroll
        for (int n = 0; n < 4; ++n) {
            p0[n][0] = cvt_pk(fmaxf(acc0[n][0], 0.f), fmaxf(acc0[n][1], 0.f));
            p0[n][1] = cvt_pk(fmaxf(acc0[n][2], 0.f), fmaxf(acc0[n][3], 0.f));
            p1[n][0] = cvt_pk(fmaxf(acc1[n][0], 0.f), fmaxf(acc1[n][1], 0.f));
            p1[n][1] = cvt_pk(fmaxf(acc1[n][2], 0.f), fmaxf(acc1[n][3], 0.f));
        }
        bf8 Blo0 = __builtin_bit_cast(bf8, uint4v{p0[0][0], p0[0][1], p0[1][0], p0[1][1]});
        bf8 Bhi0 = __builtin_bit_cast(bf8, uint4v{p0[2][0], p0[2][1], p0[3][0], p0[3][1]});
        bf8 Blo1 = __builtin_bit_cast(bf8, uint4v{p1[0][0], p1[0][1], p1[1][0], p1[1][1]});
        bf8 Bhi1 = __builtin_bit_cast(bf8, uint4v{p1[2][0], p1[2][1], p1[3][0], p1[3][1]});

        // ---- L1 (weights in regs) ----
#pragma unroll
        for (int n = 0; n < 4; ++n) {
            acc0[n] = __builtin_amdgcn_mfma_f32_16x16x32_bf16(wf1f[n][0], Blo0, b1f[n], 0, 0, 0);
            acc1[n] = __builtin_amdgcn_mfma_f32_16x16x32_bf16(wf1f[n][0], Blo1, b1f[n], 0, 0, 0);
            acc0[n] = __builtin_amdgcn_mfma_f32_16x16x32_bf16(wf1f[n][1], Bhi0, acc0[n], 0, 0, 0);
            acc1[n] = __builtin_amdgcn_mfma_f32_16x16x32_bf16(wf1f[n][1], Bhi1, acc1[n], 0, 0, 0);
            asm("" : "+v"(acc0[n]));
            asm("" : "+v"(acc1[n]));
        }
#pragma unroll
        for (int n = 0; n < 4; ++n) {
            p0[n][0] = cvt_pk(fmaxf(acc0[n][0], 0.f), fmaxf(acc0[n][1], 0.f));
            p0[n][1] = cvt_pk(fmaxf(acc0[n][2], 0.f), fmaxf(acc0[n][3], 0.f));
            p1[n][0] = cvt_pk(fmaxf(acc1[n][0], 0.f), fmaxf(acc1[n][1], 0.f));
            p1[n][1] = cvt_pk(fmaxf(acc1[n][2], 0.f), fmaxf(acc1[n][3], 0.f));
        }
        Blo0 = __builtin_bit_cast(bf8, uint4v{p0[0][0], p0[0][1], p0[1][0], p0[1][1]});
        Bhi0 = __builtin_bit_cast(bf8, uint4v{p0[2][0], p0[2][1], p0[3][0], p0[3][1]});
        Blo1 = __builtin_bit_cast(bf8, uint4v{p1[0][0], p1[0][1], p1[1][0], p1[1][1]});
        Bhi1 = __builtin_bit_cast(bf8, uint4v{p1[2][0], p1[2][1], p1[3][0], p1[3][1]});

        // ---- L2: W2 frags from LDS (shared by both chains; laundered offsets) ----
        {
            const char* base = (const char*)Wt2;
            bf8 w2[4];
#pragma unroll
            for (int n = 0; n < 4; ++n) {
                int a = off2[n][0];
                asm("" : "+v"(a));             // 1 v_mov; blocks LICM of the read
                w2[n] = *(const bf8*)(base + a);
            }
#pragma unroll
            for (int n = 0; n < 4; ++n) {
                acc0[n] = __builtin_amdgcn_mfma_f32_16x16x32_bf16(w2[n], Blo0, b2f[n], 0, 0, 0);
                acc1[n] = __builtin_amdgcn_mfma_f32_16x16x32_bf16(w2[n], Blo1, b2f[n], 0, 0, 0);
            }
#pragma unroll
            for (int n = 0; n < 4; ++n) {
                int a = off2[n][1];
                asm("" : "+v"(a));
                w2[n] = *(const bf8*)(base + a);
            }
#pragma unroll
            for (int n = 0; n < 4; ++n) {
                acc0[n] = __builtin_amdgcn_mfma_f32_16x16x32_bf16(w2[n], Bhi0, acc0[n], 0, 0, 0);
                acc1[n] = __builtin_amdgcn_mfma_f32_16x16x32_bf16(w2[n], Bhi1, acc1[n], 0, 0, 0);
                asm("" : "+v"(acc0[n]));
                asm("" : "+v"(acc1[n]));
            }
        }
#pragma unroll
        for (int n = 0; n < 4; ++n) {
            p0[n][0] = cvt_pk(fmaxf(acc0[n][0], 0.f), fmaxf(acc0[n][1], 0.f));
            p0[n][1] = cvt_pk(fmaxf(acc0[n][2], 0.f), fmaxf(acc0[n][3], 0.f));
            p1[n][0] = cvt_pk(fmaxf(acc1[n][0], 0.f), fmaxf(acc1[n][1], 0.f));
            p1[n][1] = cvt_pk(fmaxf(acc1[n][2], 0.f), fmaxf(acc1[n][3], 0.f));
        }
        Blo0 = __builtin_bit_cast(bf8, uint4v{p0[0][0], p0[0][1], p0[1][0], p0[1][1]});
        Bhi0 = __builtin_bit_cast(bf8, uint4v{p0[2][0], p0[2][1], p0[3][0], p0[3][1]});
        Blo1 = __builtin_bit_cast(bf8, uint4v{p1[0][0], p1[0][1], p1[1][0], p1[1][1]});
        Bhi1 = __builtin_bit_cast(bf8, uint4v{p1[2][0], p1[2][1], p1[3][0], p1[3][1]});

        // ---- L3: 2 MFMAs per tile vs broadcast w3 rows; row 0 = dot + b3 ----
        f32x4 acc3_0, acc3_1;
        acc3_0 = __builtin_amdgcn_mfma_f32_16x16x32_bf16(w3a[0], Blo0, c3,     0, 0, 0);
        acc3_1 = __builtin_amdgcn_mfma_f32_16x16x32_bf16(w3a[0], Blo1, c3,     0, 0, 0);
        acc3_0 = __builtin_amdgcn_mfma_f32_16x16x32_bf16(w3a[1], Bhi0, acc3_0, 0, 0, 0);
        acc3_1 = __builtin_amdgcn_mfma_f32_16x16x32_bf16(w3a[1], Bhi1, acc3_1, 0, 0, 0);

        if (g == 0) {
            obase[(tt)     * 64 * Odim] = acc3_0[0];
            obase[(tt + 1) * 64 * Odim] = acc3_1[0];
        }
    }
}

extern "C" void kernel_launch(void* const* d_in, const int* in_sizes, int n_in,
                              void* d_out, int out_size, void* d_ws, size_t ws_size,
                              hipStream_t stream) {
    const float* x  = (const float*)d_in[0];
    const float* W0 = (const float*)d_in[1];
    const float* b0 = (const float*)d_in[2];
    const float* W1 = (const float*)d_in[3];
    const float* b1 = (const float*)d_in[4];
    const float* W2 = (const float*)d_in[5];
    const float* b2 = (const float*)d_in[6];
    const float* W3 = (const float*)d_in[7];
    const float* b3 = (const float*)d_in[8];
    float* out = (float*)d_out;

    dim3 grid(Odim * BPT);   // 64 towers x 32 blocks = 2048 blocks
    dim3 block(256);
    towers_kernel<<<grid, block, 0, stream>>>(x, W0, b0, W1, b1, W2, b2, W3, b3, out);
}